// Round 7
// baseline (210.716 us; speedup 1.0000x reference)
//
#include <hip/hip_runtime.h>
#include <hip/hip_bf16.h>

// dims
#define NB2 128
#define LQK 256
#define DIM 256
#define NH 8
#define CC 32

typedef __bf16 bf16x8 __attribute__((ext_vector_type(8)));
typedef __bf16 bf16x4 __attribute__((ext_vector_type(4)));
typedef float f32x4 __attribute__((ext_vector_type(4)));

#define MFMA16 __builtin_amdgcn_mfma_f32_16x16x32_bf16

// LDS tile row stride (bf16): 64 k + 8 pad
#define TP 72

#define NTOK ((size_t)NB2 * LQK * NH * CC)   // 8,388,608

// ---------------- Kernel 0: weights fp32 -> bf16 --------------------------
__global__ __launch_bounds__(256) void k_wcvt(
    const float* __restrict__ Wq, const float* __restrict__ Wk,
    const float* __restrict__ Wv, const float* __restrict__ Wg,
    const float* __restrict__ Wo, __bf16* __restrict__ dst)
{
    int i = (blockIdx.x * 256 + threadIdx.x) * 4;
    int mat = i >> 16;
    int off = i & 65535;
    const float* src = (mat == 0) ? Wq : (mat == 1) ? Wk : (mat == 2) ? Wv
                      : (mat == 3) ? Wg : Wo;
    f32x4 v = *(const f32x4*)(src + off);
    __bf16* d = dst + ((size_t)mat << 16) + off;
    d[0] = (__bf16)v[0]; d[1] = (__bf16)v[1]; d[2] = (__bf16)v[2]; d[3] = (__bf16)v[3];
}

// ---------------- Kernel 1: QKVG projection (tiled GEMM, fp32 A) ----------
// grid (256 mb, 8 nb); nb>>1 : 0=q 1=g 2=k 3=v  (qd passes grouped first so
// the 134 MB qd stays L3-resident across its two passes, then kvd).
__global__ __launch_bounds__(256, 2) void k_proj(
    const float* __restrict__ qd, const float* __restrict__ kvd,
    const __bf16* __restrict__ wBF, const float* __restrict__ bg,
    __bf16* __restrict__ wsq, __bf16* __restrict__ wsk,
    __bf16* __restrict__ wsvT, __bf16* __restrict__ wsgT)
{
    __shared__ __bf16 At[2][128][TP];
    __shared__ __bf16 Bt[2][128][TP];

    const int mb = blockIdx.x, nb = blockIdx.y;
    const int t2 = nb >> 1;                      // 0=q 1=g 2=k 3=v
    const float* X = (t2 < 2) ? qd : kvd;
    const int widx = (t2 == 0) ? 0 : (t2 == 1) ? 3 : (t2 == 2) ? 1 : 2;
    const __bf16* W = wBF + ((size_t)widx << 16) + (size_t)((nb & 1) * 128) * 256;

    const int tid = threadIdx.x;
    const int lane = tid & 63, w = tid >> 6;
    const int g = lane >> 4, kg = g * 8, c0 = lane & 15;
    const int mq = (w >> 1) * 64, nq = (w & 1) * 64;
    const int m0 = mb * 128;
    const int srow = tid >> 1, shalf = (tid & 1) * 32;

    f32x4 acc[4][4] = {};
    f32x4 av[8]; bf16x8 bv[4];
    auto load_stage = [&](int kit) {
        const float* ap = X + (size_t)(m0 + srow) * DIM + kit * 64 + shalf;
#pragma unroll
        for (int j = 0; j < 8; j++) av[j] = *(const f32x4*)(ap + j * 4);
        const __bf16* bp = W + (size_t)srow * 256 + kit * 64 + shalf;
#pragma unroll
        for (int j = 0; j < 4; j++) bv[j] = *(const bf16x8*)(bp + j * 8);
    };
    auto write_stage = [&](int buf) {
#pragma unroll
        for (int j = 0; j < 4; j++) {
            bf16x8 c;
            f32x4 lo = av[j * 2], hi = av[j * 2 + 1];
            c[0] = (__bf16)lo[0]; c[1] = (__bf16)lo[1]; c[2] = (__bf16)lo[2]; c[3] = (__bf16)lo[3];
            c[4] = (__bf16)hi[0]; c[5] = (__bf16)hi[1]; c[6] = (__bf16)hi[2]; c[7] = (__bf16)hi[3];
            *(bf16x8*)(&At[buf][srow][shalf + j * 8]) = c;
            *(bf16x8*)(&Bt[buf][srow][shalf + j * 8]) = bv[j];
        }
    };

    load_stage(0);
    write_stage(0);
    __syncthreads();

#pragma unroll
    for (int kit = 0; kit < 4; kit++) {
        if (kit < 3) load_stage(kit + 1);
        const int cur = kit & 1;
#pragma unroll
        for (int ks = 0; ks < 2; ks++) {
            bf16x8 af[4], bf_[4];
#pragma unroll
            for (int mi = 0; mi < 4; mi++)
                af[mi] = *(const bf16x8*)(&At[cur][mq + mi * 16 + c0][ks * 32 + kg]);
#pragma unroll
            for (int ni = 0; ni < 4; ni++)
                bf_[ni] = *(const bf16x8*)(&Bt[cur][nq + ni * 16 + c0][ks * 32 + kg]);
#pragma unroll
            for (int mi = 0; mi < 4; mi++)
#pragma unroll
                for (int ni = 0; ni < 4; ni++)
                    acc[mi][ni] = MFMA16(af[mi], bf_[ni], acc[mi][ni], 0, 0, 0);
        }
        if (kit < 3) write_stage(cur ^ 1);
        __syncthreads();
    }

    // ---- epilogue ----
#pragma unroll
    for (int ni = 0; ni < 4; ni++) {
        const int nloc = (nb & 1) * 128 + nq + ni * 16 + c0;   // 0..255 within type
        const int h = nloc >> 5, c = nloc & 31;
        const float bg_ = (t2 == 1) ? bg[nloc] : 0.0f;
#pragma unroll
        for (int mi = 0; mi < 4; mi++) {
            const int mbase = m0 + mq + mi * 16 + g * 4;
            const int b2 = mbase >> 8;
            if (t2 == 3) {
                bf16x4 pk;
#pragma unroll
                for (int reg = 0; reg < 4; reg++) pk[reg] = (__bf16)acc[mi][ni][reg];
                *(bf16x4*)(&wsvT[((size_t)(b2 * NH + h) * CC + c) * LQK + (mbase & 255)]) = pk;
            } else if (t2 == 1) {
                bf16x4 pk;
#pragma unroll
                for (int reg = 0; reg < 4; reg++)
                    pk[reg] = (__bf16)(1.0f / (1.0f + __expf(-(acc[mi][ni][reg] + bg_))));
                *(bf16x4*)(&wsgT[((size_t)(b2 * NH + h) * CC + c) * LQK + (mbase & 255)]) = pk;
            } else {
#pragma unroll
                for (int reg = 0; reg < 4; reg++) {
                    const int l = (mbase + reg) & 255;
                    float v = acc[mi][ni][reg];
                    size_t idx = ((size_t)(b2 * NH + h) * LQK + l) * CC + c;
                    if (t2 == 0) wsq[idx] = (__bf16)(v * 0.17677669529663689f);
                    else         wsk[idx] = (__bf16)v;
                }
            }
        }
    }
}

// ---------------- Kernel 2: attention core (flash-chunked over k) ---------
// grid 4096 = b2(128)*h(8)*qt(4); 256 thr (4 waves), wave-private P.
// 4 chunks of 64 k; online softmax; next chunk's bias prefetched during
// current chunk's softmax+PV.
__global__ __launch_bounds__(256, 4) void k_attn(
    const __bf16* __restrict__ wsq, const __bf16* __restrict__ wsk,
    const __bf16* __restrict__ wsvT, const __bf16* __restrict__ wsgT,
    const float* __restrict__ bias, const float* __restrict__ nbb,
    __bf16* __restrict__ wswa)
{
    __shared__ __bf16 P[4][16][TP];

    const int bid = blockIdx.x;
    const int b2 = bid >> 5, h = (bid >> 2) & 7, qt = bid & 3;
    const int lane = threadIdx.x & 63, w = threadIdx.x >> 6;
    const int g = lane >> 4, kg = g * 8, c0 = lane & 15;
    const int qbase = qt * 64 + w * 16;
    const int q = qbase + c0;                 // this lane's q-row

    const __bf16* qp = wsq + (size_t)(b2 * NH + h) * LQK * CC;
    const __bf16* kp = wsk + (size_t)(b2 * NH + h) * LQK * CC;
    const __bf16* vT = wsvT + (size_t)(b2 * NH + h) * CC * LQK;
    const __bf16* gT = wsgT + (size_t)(b2 * NH + h) * CC * LQK;
    const float* bp = bias + ((size_t)(b2 * NH + h) * LQK + q) * LQK;
    const float* np = nbb + ((size_t)h * LQK + q) * LQK;

    bf16x8 qf = *(const bf16x8*)(qp + (size_t)q * CC + kg);

    // prefetch chunk 0 bias/nbb
    f32x4 cb[4], cn[4];
#pragma unroll
    for (int j = 0; j < 4; j++) {
        cb[j] = *(const f32x4*)(bp + j * 16 + g * 4);
        cn[j] = *(const f32x4*)(np + j * 16 + g * 4);
    }

    float m = -3.0e38f, l = 0.0f;
    f32x4 o[2] = {};

#pragma unroll
    for (int c = 0; c < 4; c++) {
        // ---- QK^T chunk, bias as MFMA C-operand ----
        f32x4 s[4];
#pragma unroll
        for (int j = 0; j < 4; j++) {
            const int nt = c * 4 + j;
            bf16x8 kf = *(const bf16x8*)(kp + (size_t)(nt * 16 + c0) * CC + kg);
            f32x4 cc;
#pragma unroll
            for (int r2 = 0; r2 < 4; r2++) cc[r2] = cb[j][r2] + cn[j][r2];
            s[j] = MFMA16(kf, qf, cc, 0, 0, 0);
        }
        // ---- prefetch next chunk's bias (hides HBM under softmax+PV) ----
        if (c < 3) {
#pragma unroll
            for (int j = 0; j < 4; j++) {
                cb[j] = *(const f32x4*)(bp + (c + 1) * 64 + j * 16 + g * 4);
                cn[j] = *(const f32x4*)(np + (c + 1) * 64 + j * 16 + g * 4);
            }
        }
        // ---- online softmax for this chunk (reduce over k) ----
        float cmax = s[0][0];
#pragma unroll
        for (int j = 0; j < 4; j++)
#pragma unroll
            for (int r2 = 0; r2 < 4; r2++) cmax = fmaxf(cmax, s[j][r2]);
        cmax = fmaxf(cmax, __shfl_xor(cmax, 16));
        cmax = fmaxf(cmax, __shfl_xor(cmax, 32));
        const float mn = fmaxf(m, cmax);
        const float r = __expf(m - mn);       // 0 on first chunk
        m = mn;
        float csum = 0.0f;
#pragma unroll
        for (int j = 0; j < 4; j++) {
            bf16x4 pk;
#pragma unroll
            for (int r2 = 0; r2 < 4; r2++) {
                float e = __expf(s[j][r2] - mn);
                csum += e;
                pk[r2] = (__bf16)e;
            }
            *(bf16x4*)(&P[w][c0][j * 16 + g * 4]) = pk;
        }
        csum += __shfl_xor(csum, 16);
        csum += __shfl_xor(csum, 32);
        l = l * r + csum;
        // ---- rescale o by per-row r ----
        float rr[4];
#pragma unroll
        for (int r2 = 0; r2 < 4; r2++) rr[r2] = __shfl(r, g * 4 + r2, 64);
#pragma unroll
        for (int vn = 0; vn < 2; vn++)
#pragma unroll
            for (int r2 = 0; r2 < 4; r2++) o[vn][r2] *= rr[r2];
        // ---- PV for this chunk ----
#pragma unroll
        for (int kt2 = 0; kt2 < 2; kt2++) {
            bf16x8 pa = *(const bf16x8*)(&P[w][c0][kt2 * 32 + kg]);
#pragma unroll
            for (int vn = 0; vn < 2; vn++) {
                bf16x8 vb = *(const bf16x8*)(vT + (size_t)(vn * 16 + c0) * LQK + c * 64 + kt2 * 32 + kg);
                o[vn] = MFMA16(pa, vb, o[vn], 0, 0, 0);
            }
        }
    }

    const float inv = 1.0f / l;
    // ---- 1/sum, gate (transposed, bf16x4), store ----
#pragma unroll
    for (int vn = 0; vn < 2; vn++) {
        const int c = vn * 16 + c0;
        bf16x4 g4 = *(const bf16x4*)(gT + (size_t)c * LQK + qbase + g * 4);
#pragma unroll
        for (int reg = 0; reg < 4; reg++) {
            const int row = qbase + g * 4 + reg;
            const float invr = __shfl(inv, g * 4 + reg, 64);
            const float val = o[vn][reg] * invr * (float)g4[reg];
            wswa[((size_t)(b2 * LQK + row)) * (NH * CC) + h * CC + c] = (__bf16)val;
        }
    }
}

// ---------------- Kernel 3: output projection (tiled GEMM) ----------------
__global__ __launch_bounds__(256, 2) void k_out(
    const __bf16* __restrict__ wa, const __bf16* __restrict__ wBF,
    const float* __restrict__ bo, float* __restrict__ out)
{
    __shared__ __bf16 At[2][128][TP];
    __shared__ __bf16 Bt[2][128][TP];

    const int mb = blockIdx.x, nb = blockIdx.y;
    const __bf16* W = wBF + ((size_t)4 << 16) + (size_t)(nb * 128) * 256;

    const int tid = threadIdx.x;
    const int lane = tid & 63, w = tid >> 6;
    const int g = lane >> 4, kg = g * 8, c0 = lane & 15;
    const int mq = (w >> 1) * 64, nq = (w & 1) * 64;
    const int m0 = mb * 128;
    const int srow = tid >> 1, shalf = (tid & 1) * 32;

    f32x4 acc[4][4] = {};
    bf16x8 av[4], bv[4];
    auto load_stage = [&](int kit) {
        const __bf16* ap = wa + (size_t)(m0 + srow) * 256 + kit * 64 + shalf;
        const __bf16* bp = W + (size_t)srow * 256 + kit * 64 + shalf;
#pragma unroll
        for (int j = 0; j < 4; j++) {
            av[j] = *(const bf16x8*)(ap + j * 8);
            bv[j] = *(const bf16x8*)(bp + j * 8);
        }
    };
    auto write_stage = [&](int buf) {
#pragma unroll
        for (int j = 0; j < 4; j++) {
            *(bf16x8*)(&At[buf][srow][shalf + j * 8]) = av[j];
            *(bf16x8*)(&Bt[buf][srow][shalf + j * 8]) = bv[j];
        }
    };

    load_stage(0);
    write_stage(0);
    __syncthreads();

#pragma unroll
    for (int kit = 0; kit < 4; kit++) {
        if (kit < 3) load_stage(kit + 1);
        const int cur = kit & 1;
#pragma unroll
        for (int ks = 0; ks < 2; ks++) {
            bf16x8 af[4], bf_[4];
#pragma unroll
            for (int mi = 0; mi < 4; mi++)
                af[mi] = *(const bf16x8*)(&At[cur][mq + mi * 16 + c0][ks * 32 + kg]);
#pragma unroll
            for (int ni = 0; ni < 4; ni++)
                bf_[ni] = *(const bf16x8*)(&Bt[cur][nq + ni * 16 + c0][ks * 32 + kg]);
#pragma unroll
            for (int mi = 0; mi < 4; mi++)
#pragma unroll
                for (int ni = 0; ni < 4; ni++)
                    acc[mi][ni] = MFMA16(af[mi], bf_[ni], acc[mi][ni], 0, 0, 0);
        }
        if (kit < 3) write_stage(cur ^ 1);
        __syncthreads();
    }

#pragma unroll
    for (int ni = 0; ni < 4; ni++) {
        const int n = nb * 128 + nq + ni * 16 + c0;
        const float bo_ = bo[n];
#pragma unroll
        for (int mi = 0; mi < 4; mi++) {
            const int mbase = m0 + mq + mi * 16 + g * 4;
#pragma unroll
            for (int reg = 0; reg < 4; reg++)
                out[(size_t)(mbase + reg) * 256 + n] = acc[mi][ni][reg] + bo_;
        }
    }
}

// ---------------- launcher ------------------------------------------------
extern "C" void kernel_launch(void* const* d_in, const int* in_sizes, int n_in,
                              void* d_out, int out_size, void* d_ws, size_t ws_size,
                              hipStream_t stream) {
    const float* qd  = (const float*)d_in[0];
    const float* kvd = (const float*)d_in[1];
    const float* bias = (const float*)d_in[2];
    const float* nbb = (const float*)d_in[3];
    const float* Wq = (const float*)d_in[4];
    const float* Wk = (const float*)d_in[5];
    const float* Wv = (const float*)d_in[6];
    const float* Wg = (const float*)d_in[7];
    const float* bg = (const float*)d_in[8];
    const float* Wo = (const float*)d_in[9];
    const float* bo = (const float*)d_in[10];
    float* out = (float*)d_out;

    __bf16* ws = (__bf16*)d_ws;
    __bf16* wsq  = ws;
    __bf16* wsk  = wsq + NTOK;
    __bf16* wsvT = wsk + NTOK;
    __bf16* wsgT = wsvT + NTOK;
    __bf16* wBF  = wsgT + NTOK;            // 5 * 65536 bf16 weights
    __bf16* wswa = wBF + 5 * 65536;

    k_wcvt<<<dim3(320), 256, 0, stream>>>(Wq, Wk, Wv, Wg, Wo, wBF);
    k_proj<<<dim3(256, 8), 256, 0, stream>>>(qd, kvd, wBF, bg,
                                             wsq, wsk, wsvT, wsgT);
    k_attn<<<dim3(4096), 256, 0, stream>>>(wsq, wsk, wsvT, wsgT, bias, nbb, wswa);
    k_out<<<dim3(256, 2), 256, 0, stream>>>(wswa, wBF, bo, out);
}

// Round 8
// 199.656 us; speedup vs baseline: 1.0554x; 1.0554x over previous
//
#include <hip/hip_runtime.h>
#include <hip/hip_bf16.h>

// dims
#define NB2 128
#define LQK 256
#define DIM 256
#define NH 8
#define CC 32

typedef __bf16 bf16x8 __attribute__((ext_vector_type(8)));
typedef __bf16 bf16x4 __attribute__((ext_vector_type(4)));
typedef float f32x4 __attribute__((ext_vector_type(4)));

#define MFMA16 __builtin_amdgcn_mfma_f32_16x16x32_bf16

// LDS tile row stride (bf16): 64 k + 8 pad
#define TP 72

#define NTOK ((size_t)NB2 * LQK * NH * CC)   // 8,388,608

// ---------------- Kernel 0a: weights fp32 -> bf16 -------------------------
__global__ __launch_bounds__(256) void k_wcvt(
    const float* __restrict__ Wq, const float* __restrict__ Wk,
    const float* __restrict__ Wv, const float* __restrict__ Wg,
    const float* __restrict__ Wo, __bf16* __restrict__ dst)
{
    int i = (blockIdx.x * 256 + threadIdx.x) * 4;
    int mat = i >> 16;
    int off = i & 65535;
    const float* src = (mat == 0) ? Wq : (mat == 1) ? Wk : (mat == 2) ? Wv
                      : (mat == 3) ? Wg : Wo;
    f32x4 v = *(const f32x4*)(src + off);
    __bf16* d = dst + ((size_t)mat << 16) + off;
    d[0] = (__bf16)v[0]; d[1] = (__bf16)v[1]; d[2] = (__bf16)v[2]; d[3] = (__bf16)v[3];
}

// ---------------- Kernel 0b: activations fp32 -> bf16 ---------------------
__global__ __launch_bounds__(256) void k_acvt(
    const float* __restrict__ qd, const float* __restrict__ kvd,
    __bf16* __restrict__ qbf, __bf16* __restrict__ kvbf)
{
    size_t i = ((size_t)blockIdx.x * 256 + threadIdx.x) * 8;
    const float* src;
    __bf16* dst;
    if (i < NTOK) { src = qd + i; dst = qbf + i; }
    else          { src = kvd + (i - NTOK); dst = kvbf + (i - NTOK); }
    f32x4 a = *(const f32x4*)src;
    f32x4 b = *(const f32x4*)(src + 4);
    bf16x8 r;
    r[0] = (__bf16)a[0]; r[1] = (__bf16)a[1]; r[2] = (__bf16)a[2]; r[3] = (__bf16)a[3];
    r[4] = (__bf16)b[0]; r[5] = (__bf16)b[1]; r[6] = (__bf16)b[2]; r[7] = (__bf16)b[3];
    *(bf16x8*)dst = r;
}

// ---------------- Kernel 1: QKVG projection (tiled GEMM, bf16 A) ----------
__global__ __launch_bounds__(256, 2) void k_proj(
    const __bf16* __restrict__ qbf, const __bf16* __restrict__ kvbf,
    const __bf16* __restrict__ wBF, const float* __restrict__ bg,
    __bf16* __restrict__ wsq, __bf16* __restrict__ wsk,
    __bf16* __restrict__ wsvT, __bf16* __restrict__ wsgT)
{
    __shared__ __bf16 At[2][128][TP];
    __shared__ __bf16 Bt[2][128][TP];

    const int mb = blockIdx.x, nb = blockIdx.y;
    const int t = nb >> 1;                       // 0=q 1=k 2=v 3=g
    const __bf16* X = (t == 0 || t == 3) ? qbf : kvbf;
    const __bf16* W = wBF + ((size_t)t << 16) + (size_t)((nb & 1) * 128) * 256;

    const int tid = threadIdx.x;
    const int lane = tid & 63, w = tid >> 6;
    const int g = lane >> 4, kg = g * 8, c0 = lane & 15;
    const int mq = (w >> 1) * 64, nq = (w & 1) * 64;
    const int m0 = mb * 128;
    const int srow = tid >> 1, shalf = (tid & 1) * 32;

    f32x4 acc[4][4] = {};
    bf16x8 av[4], bv[4];
    auto load_stage = [&](int kit) {
        const __bf16* ap = X + (size_t)(m0 + srow) * DIM + kit * 64 + shalf;
        const __bf16* bp = W + (size_t)srow * 256 + kit * 64 + shalf;
#pragma unroll
        for (int j = 0; j < 4; j++) {
            av[j] = *(const bf16x8*)(ap + j * 8);
            bv[j] = *(const bf16x8*)(bp + j * 8);
        }
    };
    auto write_stage = [&](int buf) {
#pragma unroll
        for (int j = 0; j < 4; j++) {
            *(bf16x8*)(&At[buf][srow][shalf + j * 8]) = av[j];
            *(bf16x8*)(&Bt[buf][srow][shalf + j * 8]) = bv[j];
        }
    };

    load_stage(0);
    write_stage(0);
    __syncthreads();

#pragma unroll
    for (int kit = 0; kit < 4; kit++) {
        if (kit < 3) load_stage(kit + 1);
        const int cur = kit & 1;
#pragma unroll
        for (int ks = 0; ks < 2; ks++) {
            bf16x8 af[4], bf_[4];
#pragma unroll
            for (int mi = 0; mi < 4; mi++)
                af[mi] = *(const bf16x8*)(&At[cur][mq + mi * 16 + c0][ks * 32 + kg]);
#pragma unroll
            for (int ni = 0; ni < 4; ni++)
                bf_[ni] = *(const bf16x8*)(&Bt[cur][nq + ni * 16 + c0][ks * 32 + kg]);
#pragma unroll
            for (int mi = 0; mi < 4; mi++)
#pragma unroll
                for (int ni = 0; ni < 4; ni++)
                    acc[mi][ni] = MFMA16(af[mi], bf_[ni], acc[mi][ni], 0, 0, 0);
        }
        if (kit < 3) write_stage(cur ^ 1);
        __syncthreads();
    }

    // ---- epilogue ----
#pragma unroll
    for (int ni = 0; ni < 4; ni++) {
        const int nloc = (nb & 1) * 128 + nq + ni * 16 + c0;
        const int h = nloc >> 5, c = nloc & 31;
        const float bg_ = (t == 3) ? bg[nloc] : 0.0f;
#pragma unroll
        for (int mi = 0; mi < 4; mi++) {
            const int mbase = m0 + mq + mi * 16 + g * 4;
            const int b2 = mbase >> 8;
            if (t == 2) {
                bf16x4 pk;
#pragma unroll
                for (int reg = 0; reg < 4; reg++) pk[reg] = (__bf16)acc[mi][ni][reg];
                *(bf16x4*)(&wsvT[((size_t)(b2 * NH + h) * CC + c) * LQK + (mbase & 255)]) = pk;
            } else if (t == 3) {
                bf16x4 pk;
#pragma unroll
                for (int reg = 0; reg < 4; reg++)
                    pk[reg] = (__bf16)(1.0f / (1.0f + __expf(-(acc[mi][ni][reg] + bg_))));
                *(bf16x4*)(&wsgT[((size_t)(b2 * NH + h) * CC + c) * LQK + (mbase & 255)]) = pk;
            } else {
#pragma unroll
                for (int reg = 0; reg < 4; reg++) {
                    const int l = (mbase + reg) & 255;
                    float v = acc[mi][ni][reg];
                    size_t idx = ((size_t)(b2 * NH + h) * LQK + l) * CC + c;
                    if (t == 0) wsq[idx] = (__bf16)(v * 0.17677669529663689f);
                    else        wsk[idx] = (__bf16)v;
                }
            }
        }
    }
}

// ---------------- Kernel 2: attention (no-max softmax, FIFO pipeline) -----
// grid 4096 = b2(128)*h(8)*qt(4); 256 thr (4 waves), wave-private P.
// 4 chunks of 64 k. Per chunk, issue order == consume order:
//   [vf loads (this chunk)] [bias/nbb/kf prefetch (next chunk)] [compute]
// so PV's vmcnt wait leaves the prefetch in flight.
__global__ __launch_bounds__(256, 3) void k_attn(
    const __bf16* __restrict__ wsq, const __bf16* __restrict__ wsk,
    const __bf16* __restrict__ wsvT, const __bf16* __restrict__ wsgT,
    const float* __restrict__ bias, const float* __restrict__ nbb,
    __bf16* __restrict__ wswa)
{
    __shared__ __bf16 P[4][16][TP];

    const int bid = blockIdx.x;
    const int b2 = bid >> 5, h = (bid >> 2) & 7, qt = bid & 3;
    const int lane = threadIdx.x & 63, w = threadIdx.x >> 6;
    const int g = lane >> 4, kg = g * 8, c0 = lane & 15;
    const int qbase = qt * 64 + w * 16;
    const int q = qbase + c0;                 // this lane's q-row

    const __bf16* qp = wsq + (size_t)(b2 * NH + h) * LQK * CC;
    const __bf16* kp = wsk + (size_t)(b2 * NH + h) * LQK * CC;
    const __bf16* vT = wsvT + (size_t)(b2 * NH + h) * CC * LQK;
    const __bf16* gT = wsgT + (size_t)(b2 * NH + h) * CC * LQK;
    const float* bp = bias + ((size_t)(b2 * NH + h) * LQK + q) * LQK;
    const float* np = nbb + ((size_t)h * LQK + q) * LQK;

    bf16x8 qf = *(const bf16x8*)(qp + (size_t)q * CC + kg);

    // prologue: chunk-0 bias/nbb/kf
    f32x4 cb[2][4], cn[2][4];
    bf16x8 kf[2][4];
#pragma unroll
    for (int j = 0; j < 4; j++) {
        cb[0][j] = *(const f32x4*)(bp + j * 16 + g * 4);
        cn[0][j] = *(const f32x4*)(np + j * 16 + g * 4);
        kf[0][j] = *(const bf16x8*)(kp + (size_t)(j * 16 + c0) * CC + kg);
    }

    float l = 0.0f;
    f32x4 o[2] = {};

#pragma unroll
    for (int c = 0; c < 4; c++) {
        const int cur = c & 1, nxt = cur ^ 1;
        // (1) vf loads for THIS chunk (consumed at the end of this chunk)
        bf16x8 vf[4];
#pragma unroll
        for (int kt2 = 0; kt2 < 2; kt2++)
#pragma unroll
            for (int vn = 0; vn < 2; vn++)
                vf[kt2 * 2 + vn] = *(const bf16x8*)(vT + (size_t)(vn * 16 + c0) * LQK + c * 64 + kt2 * 32 + kg);
        // (2) prefetch NEXT chunk's bias/nbb/kf (consumed next iteration)
        if (c < 3) {
#pragma unroll
            for (int j = 0; j < 4; j++) {
                cb[nxt][j] = *(const f32x4*)(bp + (c + 1) * 64 + j * 16 + g * 4);
                cn[nxt][j] = *(const f32x4*)(np + (c + 1) * 64 + j * 16 + g * 4);
                kf[nxt][j] = *(const bf16x8*)(kp + (size_t)(((c + 1) * 4 + j) * 16 + c0) * CC + kg);
            }
        }
        // (3) compute chunk c from registers
        float csum = 0.0f;
#pragma unroll
        for (int j = 0; j < 4; j++) {
            f32x4 cc;
#pragma unroll
            for (int r2 = 0; r2 < 4; r2++) cc[r2] = cb[cur][j][r2] + cn[cur][j][r2];
            f32x4 s = MFMA16(kf[cur][j], qf, cc, 0, 0, 0);
            bf16x4 pk;
#pragma unroll
            for (int r2 = 0; r2 < 4; r2++) {
                float e = __expf(s[r2]);      // no max-sub: |s| bounded ~20
                csum += e;
                pk[r2] = (__bf16)e;
            }
            *(bf16x4*)(&P[w][c0][j * 16 + g * 4]) = pk;
        }
        l += csum;
#pragma unroll
        for (int kt2 = 0; kt2 < 2; kt2++) {
            bf16x8 pa = *(const bf16x8*)(&P[w][c0][kt2 * 32 + kg]);
#pragma unroll
            for (int vn = 0; vn < 2; vn++)
                o[vn] = MFMA16(pa, vf[kt2 * 2 + vn], o[vn], 0, 0, 0);
        }
    }

    l += __shfl_xor(l, 16);
    l += __shfl_xor(l, 32);
    const float inv = 1.0f / l;

    // ---- 1/sum, gate (transposed, bf16x4), store ----
#pragma unroll
    for (int vn = 0; vn < 2; vn++) {
        const int c = vn * 16 + c0;
        bf16x4 g4 = *(const bf16x4*)(gT + (size_t)c * LQK + qbase + g * 4);
#pragma unroll
        for (int reg = 0; reg < 4; reg++) {
            const int row = qbase + g * 4 + reg;
            const float invr = __shfl(inv, g * 4 + reg, 64);
            const float val = o[vn][reg] * invr * (float)g4[reg];
            wswa[((size_t)(b2 * LQK + row)) * (NH * CC) + h * CC + c] = (__bf16)val;
        }
    }
}

// ---------------- Kernel 3: output projection (tiled GEMM) ----------------
__global__ __launch_bounds__(256, 2) void k_out(
    const __bf16* __restrict__ wa, const __bf16* __restrict__ wBF,
    const float* __restrict__ bo, float* __restrict__ out)
{
    __shared__ __bf16 At[2][128][TP];
    __shared__ __bf16 Bt[2][128][TP];

    const int mb = blockIdx.x, nb = blockIdx.y;
    const __bf16* W = wBF + ((size_t)4 << 16) + (size_t)(nb * 128) * 256;

    const int tid = threadIdx.x;
    const int lane = tid & 63, w = tid >> 6;
    const int g = lane >> 4, kg = g * 8, c0 = lane & 15;
    const int mq = (w >> 1) * 64, nq = (w & 1) * 64;
    const int m0 = mb * 128;
    const int srow = tid >> 1, shalf = (tid & 1) * 32;

    f32x4 acc[4][4] = {};
    bf16x8 av[4], bv[4];
    auto load_stage = [&](int kit) {
        const __bf16* ap = wa + (size_t)(m0 + srow) * 256 + kit * 64 + shalf;
        const __bf16* bp = W + (size_t)srow * 256 + kit * 64 + shalf;
#pragma unroll
        for (int j = 0; j < 4; j++) {
            av[j] = *(const bf16x8*)(ap + j * 8);
            bv[j] = *(const bf16x8*)(bp + j * 8);
        }
    };
    auto write_stage = [&](int buf) {
#pragma unroll
        for (int j = 0; j < 4; j++) {
            *(bf16x8*)(&At[buf][srow][shalf + j * 8]) = av[j];
            *(bf16x8*)(&Bt[buf][srow][shalf + j * 8]) = bv[j];
        }
    };

    load_stage(0);
    write_stage(0);
    __syncthreads();

#pragma unroll
    for (int kit = 0; kit < 4; kit++) {
        if (kit < 3) load_stage(kit + 1);
        const int cur = kit & 1;
#pragma unroll
        for (int ks = 0; ks < 2; ks++) {
            bf16x8 af[4], bf_[4];
#pragma unroll
            for (int mi = 0; mi < 4; mi++)
                af[mi] = *(const bf16x8*)(&At[cur][mq + mi * 16 + c0][ks * 32 + kg]);
#pragma unroll
            for (int ni = 0; ni < 4; ni++)
                bf_[ni] = *(const bf16x8*)(&Bt[cur][nq + ni * 16 + c0][ks * 32 + kg]);
#pragma unroll
            for (int mi = 0; mi < 4; mi++)
#pragma unroll
                for (int ni = 0; ni < 4; ni++)
                    acc[mi][ni] = MFMA16(af[mi], bf_[ni], acc[mi][ni], 0, 0, 0);
        }
        if (kit < 3) write_stage(cur ^ 1);
        __syncthreads();
    }

#pragma unroll
    for (int ni = 0; ni < 4; ni++) {
        const int n = nb * 128 + nq + ni * 16 + c0;
        const float bo_ = bo[n];
#pragma unroll
        for (int mi = 0; mi < 4; mi++) {
            const int mbase = m0 + mq + mi * 16 + g * 4;
#pragma unroll
            for (int reg = 0; reg < 4; reg++)
                out[(size_t)(mbase + reg) * 256 + n] = acc[mi][ni][reg] + bo_;
        }
    }
}

// ---------------- launcher ------------------------------------------------
extern "C" void kernel_launch(void* const* d_in, const int* in_sizes, int n_in,
                              void* d_out, int out_size, void* d_ws, size_t ws_size,
                              hipStream_t stream) {
    const float* qd  = (const float*)d_in[0];
    const float* kvd = (const float*)d_in[1];
    const float* bias = (const float*)d_in[2];
    const float* nbb = (const float*)d_in[3];
    const float* Wq = (const float*)d_in[4];
    const float* Wk = (const float*)d_in[5];
    const float* Wv = (const float*)d_in[6];
    const float* Wg = (const float*)d_in[7];
    const float* bg = (const float*)d_in[8];
    const float* Wo = (const float*)d_in[9];
    const float* bo = (const float*)d_in[10];
    float* out = (float*)d_out;

    __bf16* ws = (__bf16*)d_ws;
    __bf16* wsq  = ws;
    __bf16* wsk  = wsq + NTOK;
    __bf16* wsvT = wsk + NTOK;
    __bf16* wsgT = wsvT + NTOK;
    __bf16* wBF  = wsgT + NTOK;            // 5 * 65536 bf16 weights
    __bf16* qbf  = wBF + 5 * 65536;        // activations bf16 (dead after k_proj)
    __bf16* kvbf = qbf + NTOK;
    __bf16* wswa = qbf;                    // alias: written by k_attn after k_proj

    k_wcvt<<<dim3(320), 256, 0, stream>>>(Wq, Wk, Wv, Wg, Wo, wBF);
    k_acvt<<<dim3(8192), 256, 0, stream>>>(qd, kvd, qbf, kvbf);
    k_proj<<<dim3(256, 8), 256, 0, stream>>>(qbf, kvbf, wBF, bg,
                                             wsq, wsk, wsvT, wsgT);
    k_attn<<<dim3(4096), 256, 0, stream>>>(wsq, wsk, wsvT, wsgT, bias, nbb, wswa);
    k_out<<<dim3(256, 2), 256, 0, stream>>>(wswa, wBF, bo, out);
}

// Round 9
// 186.028 us; speedup vs baseline: 1.1327x; 1.0733x over previous
//
#include <hip/hip_runtime.h>
#include <hip/hip_bf16.h>

// dims
#define NB2 128
#define LQK 256
#define DIM 256
#define NH 8
#define CC 32

typedef __bf16 bf16x8 __attribute__((ext_vector_type(8)));
typedef __bf16 bf16x4 __attribute__((ext_vector_type(4)));
typedef float f32x4 __attribute__((ext_vector_type(4)));

#define MFMA16 __builtin_amdgcn_mfma_f32_16x16x32_bf16

// LDS tile row stride (bf16): 64 k + 8 pad
#define TP 72

#define NTOK ((size_t)NB2 * LQK * NH * CC)   // 8,388,608

// async global->LDS, 16B per lane; LDS dest is wave-uniform base + lane*16
static __device__ __forceinline__ void gload_lds16(const void* g, void* l) {
    __builtin_amdgcn_global_load_lds(
        (const __attribute__((address_space(1))) unsigned int*)g,
        (__attribute__((address_space(3))) unsigned int*)l,
        16, 0, 0);
}

// ---------------- Kernel 0a: weights fp32 -> bf16 -------------------------
__global__ __launch_bounds__(256) void k_wcvt(
    const float* __restrict__ Wq, const float* __restrict__ Wk,
    const float* __restrict__ Wv, const float* __restrict__ Wg,
    const float* __restrict__ Wo, __bf16* __restrict__ dst)
{
    int i = (blockIdx.x * 256 + threadIdx.x) * 4;
    int mat = i >> 16;
    int off = i & 65535;
    const float* src = (mat == 0) ? Wq : (mat == 1) ? Wk : (mat == 2) ? Wv
                      : (mat == 3) ? Wg : Wo;
    f32x4 v = *(const f32x4*)(src + off);
    __bf16* d = dst + ((size_t)mat << 16) + off;
    d[0] = (__bf16)v[0]; d[1] = (__bf16)v[1]; d[2] = (__bf16)v[2]; d[3] = (__bf16)v[3];
}

// ---------------- Kernel 0b: activations fp32 -> bf16 ---------------------
__global__ __launch_bounds__(256) void k_acvt(
    const float* __restrict__ qd, const float* __restrict__ kvd,
    __bf16* __restrict__ qbf, __bf16* __restrict__ kvbf)
{
    size_t i = ((size_t)blockIdx.x * 256 + threadIdx.x) * 8;
    const float* src;
    __bf16* dst;
    if (i < NTOK) { src = qd + i; dst = qbf + i; }
    else          { src = kvd + (i - NTOK); dst = kvbf + (i - NTOK); }
    f32x4 a = *(const f32x4*)src;
    f32x4 b = *(const f32x4*)(src + 4);
    bf16x8 r;
    r[0] = (__bf16)a[0]; r[1] = (__bf16)a[1]; r[2] = (__bf16)a[2]; r[3] = (__bf16)a[3];
    r[4] = (__bf16)b[0]; r[5] = (__bf16)b[1]; r[6] = (__bf16)b[2]; r[7] = (__bf16)b[3];
    *(bf16x8*)dst = r;
}

// ---------------- Kernel 1: QKVG projection (tiled GEMM, bf16 A) ----------
__global__ __launch_bounds__(256, 2) void k_proj(
    const __bf16* __restrict__ qbf, const __bf16* __restrict__ kvbf,
    const __bf16* __restrict__ wBF, const float* __restrict__ bg,
    __bf16* __restrict__ wsq, __bf16* __restrict__ wsk,
    __bf16* __restrict__ wsvT, __bf16* __restrict__ wsgT)
{
    __shared__ __bf16 At[2][128][TP];
    __shared__ __bf16 Bt[2][128][TP];

    const int mb = blockIdx.x, nb = blockIdx.y;
    const int t = nb >> 1;                       // 0=q 1=k 2=v 3=g
    const __bf16* X = (t == 0 || t == 3) ? qbf : kvbf;
    const __bf16* W = wBF + ((size_t)t << 16) + (size_t)((nb & 1) * 128) * 256;

    const int tid = threadIdx.x;
    const int lane = tid & 63, w = tid >> 6;
    const int g = lane >> 4, kg = g * 8, c0 = lane & 15;
    const int mq = (w >> 1) * 64, nq = (w & 1) * 64;
    const int m0 = mb * 128;
    const int srow = tid >> 1, shalf = (tid & 1) * 32;

    f32x4 acc[4][4] = {};
    bf16x8 av[4], bv[4];
    auto load_stage = [&](int kit) {
        const __bf16* ap = X + (size_t)(m0 + srow) * DIM + kit * 64 + shalf;
        const __bf16* bp = W + (size_t)srow * 256 + kit * 64 + shalf;
#pragma unroll
        for (int j = 0; j < 4; j++) {
            av[j] = *(const bf16x8*)(ap + j * 8);
            bv[j] = *(const bf16x8*)(bp + j * 8);
        }
    };
    auto write_stage = [&](int buf) {
#pragma unroll
        for (int j = 0; j < 4; j++) {
            *(bf16x8*)(&At[buf][srow][shalf + j * 8]) = av[j];
            *(bf16x8*)(&Bt[buf][srow][shalf + j * 8]) = bv[j];
        }
    };

    load_stage(0);
    write_stage(0);
    __syncthreads();

#pragma unroll
    for (int kit = 0; kit < 4; kit++) {
        if (kit < 3) load_stage(kit + 1);
        const int cur = kit & 1;
#pragma unroll
        for (int ks = 0; ks < 2; ks++) {
            bf16x8 af[4], bf_[4];
#pragma unroll
            for (int mi = 0; mi < 4; mi++)
                af[mi] = *(const bf16x8*)(&At[cur][mq + mi * 16 + c0][ks * 32 + kg]);
#pragma unroll
            for (int ni = 0; ni < 4; ni++)
                bf_[ni] = *(const bf16x8*)(&Bt[cur][nq + ni * 16 + c0][ks * 32 + kg]);
#pragma unroll
            for (int mi = 0; mi < 4; mi++)
#pragma unroll
                for (int ni = 0; ni < 4; ni++)
                    acc[mi][ni] = MFMA16(af[mi], bf_[ni], acc[mi][ni], 0, 0, 0);
        }
        if (kit < 3) write_stage(cur ^ 1);
        __syncthreads();
    }

    // ---- epilogue ----
#pragma unroll
    for (int ni = 0; ni < 4; ni++) {
        const int nloc = (nb & 1) * 128 + nq + ni * 16 + c0;
        const int h = nloc >> 5, c = nloc & 31;
        const float bg_ = (t == 3) ? bg[nloc] : 0.0f;
#pragma unroll
        for (int mi = 0; mi < 4; mi++) {
            const int mbase = m0 + mq + mi * 16 + g * 4;
            const int b2 = mbase >> 8;
            if (t == 2) {
                bf16x4 pk;
#pragma unroll
                for (int reg = 0; reg < 4; reg++) pk[reg] = (__bf16)acc[mi][ni][reg];
                *(bf16x4*)(&wsvT[((size_t)(b2 * NH + h) * CC + c) * LQK + (mbase & 255)]) = pk;
            } else if (t == 3) {
                bf16x4 pk;
#pragma unroll
                for (int reg = 0; reg < 4; reg++)
                    pk[reg] = (__bf16)(1.0f / (1.0f + __expf(-(acc[mi][ni][reg] + bg_))));
                *(bf16x4*)(&wsgT[((size_t)(b2 * NH + h) * CC + c) * LQK + (mbase & 255)]) = pk;
            } else {
#pragma unroll
                for (int reg = 0; reg < 4; reg++) {
                    const int l = (mbase + reg) & 255;
                    float v = acc[mi][ni][reg];
                    size_t idx = ((size_t)(b2 * NH + h) * LQK + l) * CC + c;
                    if (t == 0) wsq[idx] = (__bf16)(v * 0.17677669529663689f);
                    else        wsk[idx] = (__bf16)v;
                }
            }
        }
    }
}

// ---------------- Kernel 2: attention (bias via async global_load_lds) ----
// grid 4096 = b2(128)*h(8)*qt(4); 256 thr (4 waves).
// 4 chunks of 64 k; bias[64q][64k] fp32 double-buffered in LDS, staged by
// 4 block-wide global_load_lds per chunk (XOR-swizzled src, swizzled read).
__global__ __launch_bounds__(256, 3) void k_attn(
    const __bf16* __restrict__ wsq, const __bf16* __restrict__ wsk,
    const __bf16* __restrict__ wsvT, const __bf16* __restrict__ wsgT,
    const float* __restrict__ bias, const float* __restrict__ nbb,
    __bf16* __restrict__ wswa)
{
    __shared__ float Bl[2][64][64];     // 32 KB bias double-buffer (linear)
    __shared__ __bf16 P[4][16][TP];     // wave-private P strips

    const int tid = threadIdx.x;
    const int bid = blockIdx.x;
    const int b2 = bid >> 5, h = (bid >> 2) & 7, qt = bid & 3;
    const int lane = tid & 63, w = tid >> 6;
    const int g = lane >> 4, kg = g * 8, c0 = lane & 15;
    const int qbase = qt * 64 + w * 16;
    const int q = qbase + c0;                 // this lane's q-row
    const int rw = w * 16 + c0;               // q-row within block (0..63)

    const __bf16* qp = wsq + (size_t)(b2 * NH + h) * LQK * CC;
    const __bf16* kp = wsk + (size_t)(b2 * NH + h) * LQK * CC;
    const __bf16* vT = wsvT + (size_t)(b2 * NH + h) * CC * LQK;
    const __bf16* gT = wsgT + (size_t)(b2 * NH + h) * CC * LQK;
    const float* np = nbb + ((size_t)h * LQK + q) * LQK;
    // block's bias panel base: rows qt*64 .. +63
    const float* bblk = bias + ((size_t)(b2 * NH + h) * LQK + qt * 64) * LQK;

    // stage bias chunk c into Bl[buf]: 4 x (256 thr x 16B) = 16 KB
    // row r = i*16 + (tid>>4); source unit XOR-swizzled by (r&7)
    auto stage = [&](int buf, int c) {
        const int rbase = tid >> 4;           // 0..15
        const int jj = tid & 15;
#pragma unroll
        for (int i = 0; i < 4; i++) {
            const int row = i * 16 + rbase;   // 0..63
            const int u = jj ^ (row & 7);
            const float* src = bblk + (size_t)row * LQK + c * 64 + u * 4;
            gload_lds16(src, &Bl[buf][i * 16 + w * 4][0]);
        }
    };

    bf16x8 qf = *(const bf16x8*)(qp + (size_t)q * CC + kg);

    stage(0, 0);
    __syncthreads();

    float l = 0.0f;
    f32x4 o[2] = {};

#pragma unroll
    for (int c = 0; c < 4; c++) {
        const int cur = c & 1;
        if (c < 3) stage(cur ^ 1, c + 1);     // async, drains at the barrier

        float csum = 0.0f;
#pragma unroll
        for (int j = 0; j < 4; j++) {
            // bias from LDS (swizzled read) + nbb direct (L2-hot)
            const int su = ((j * 4 + g) ^ (rw & 7)) * 4;
            f32x4 b4 = *(const f32x4*)(&Bl[cur][rw][su]);
            f32x4 n4 = *(const f32x4*)(np + c * 64 + j * 16 + g * 4);
            bf16x8 kf = *(const bf16x8*)(kp + (size_t)((c * 4 + j) * 16 + c0) * CC + kg);
            f32x4 cc;
#pragma unroll
            for (int r2 = 0; r2 < 4; r2++) cc[r2] = b4[r2] + n4[r2];
            f32x4 s = MFMA16(kf, qf, cc, 0, 0, 0);
            bf16x4 pk;
#pragma unroll
            for (int r2 = 0; r2 < 4; r2++) {
                float e = __expf(s[r2]);      // no max-sub: |s| bounded ~20
                csum += e;
                pk[r2] = (__bf16)e;
            }
            *(bf16x4*)(&P[w][c0][j * 16 + g * 4]) = pk;
        }
        l += csum;
#pragma unroll
        for (int kt2 = 0; kt2 < 2; kt2++) {
            bf16x8 pa = *(const bf16x8*)(&P[w][c0][kt2 * 32 + kg]);
#pragma unroll
            for (int vn = 0; vn < 2; vn++) {
                bf16x8 vb = *(const bf16x8*)(vT + (size_t)(vn * 16 + c0) * LQK + c * 64 + kt2 * 32 + kg);
                o[vn] = MFMA16(pa, vb, o[vn], 0, 0, 0);
            }
        }
        if (c < 3) __syncthreads();           // drains stage(c+1); dbuf safety
    }

    l += __shfl_xor(l, 16);
    l += __shfl_xor(l, 32);
    const float inv = 1.0f / l;

    // ---- 1/sum, gate (transposed, bf16x4), store ----
#pragma unroll
    for (int vn = 0; vn < 2; vn++) {
        const int c = vn * 16 + c0;
        bf16x4 g4 = *(const bf16x4*)(gT + (size_t)c * LQK + qbase + g * 4);
#pragma unroll
        for (int reg = 0; reg < 4; reg++) {
            const int row = qbase + g * 4 + reg;
            const float invr = __shfl(inv, g * 4 + reg, 64);
            const float val = o[vn][reg] * invr * (float)g4[reg];
            wswa[((size_t)(b2 * LQK + row)) * (NH * CC) + h * CC + c] = (__bf16)val;
        }
    }
}

// ---------------- Kernel 3: output projection (tiled GEMM) ----------------
__global__ __launch_bounds__(256, 2) void k_out(
    const __bf16* __restrict__ wa, const __bf16* __restrict__ wBF,
    const float* __restrict__ bo, float* __restrict__ out)
{
    __shared__ __bf16 At[2][128][TP];
    __shared__ __bf16 Bt[2][128][TP];

    const int mb = blockIdx.x, nb = blockIdx.y;
    const __bf16* W = wBF + ((size_t)4 << 16) + (size_t)(nb * 128) * 256;

    const int tid = threadIdx.x;
    const int lane = tid & 63, w = tid >> 6;
    const int g = lane >> 4, kg = g * 8, c0 = lane & 15;
    const int mq = (w >> 1) * 64, nq = (w & 1) * 64;
    const int m0 = mb * 128;
    const int srow = tid >> 1, shalf = (tid & 1) * 32;

    f32x4 acc[4][4] = {};
    bf16x8 av[4], bv[4];
    auto load_stage = [&](int kit) {
        const __bf16* ap = wa + (size_t)(m0 + srow) * 256 + kit * 64 + shalf;
        const __bf16* bp = W + (size_t)srow * 256 + kit * 64 + shalf;
#pragma unroll
        for (int j = 0; j < 4; j++) {
            av[j] = *(const bf16x8*)(ap + j * 8);
            bv[j] = *(const bf16x8*)(bp + j * 8);
        }
    };
    auto write_stage = [&](int buf) {
#pragma unroll
        for (int j = 0; j < 4; j++) {
            *(bf16x8*)(&At[buf][srow][shalf + j * 8]) = av[j];
            *(bf16x8*)(&Bt[buf][srow][shalf + j * 8]) = bv[j];
        }
    };

    load_stage(0);
    write_stage(0);
    __syncthreads();

#pragma unroll
    for (int kit = 0; kit < 4; kit++) {
        if (kit < 3) load_stage(kit + 1);
        const int cur = kit & 1;
#pragma unroll
        for (int ks = 0; ks < 2; ks++) {
            bf16x8 af[4], bf_[4];
#pragma unroll
            for (int mi = 0; mi < 4; mi++)
                af[mi] = *(const bf16x8*)(&At[cur][mq + mi * 16 + c0][ks * 32 + kg]);
#pragma unroll
            for (int ni = 0; ni < 4; ni++)
                bf_[ni] = *(const bf16x8*)(&Bt[cur][nq + ni * 16 + c0][ks * 32 + kg]);
#pragma unroll
            for (int mi = 0; mi < 4; mi++)
#pragma unroll
                for (int ni = 0; ni < 4; ni++)
                    acc[mi][ni] = MFMA16(af[mi], bf_[ni], acc[mi][ni], 0, 0, 0);
        }
        if (kit < 3) write_stage(cur ^ 1);
        __syncthreads();
    }

#pragma unroll
    for (int ni = 0; ni < 4; ni++) {
        const int n = nb * 128 + nq + ni * 16 + c0;
        const float bo_ = bo[n];
#pragma unroll
        for (int mi = 0; mi < 4; mi++) {
            const int mbase = m0 + mq + mi * 16 + g * 4;
#pragma unroll
            for (int reg = 0; reg < 4; reg++)
                out[(size_t)(mbase + reg) * 256 + n] = acc[mi][ni][reg] + bo_;
        }
    }
}

// ---------------- launcher ------------------------------------------------
extern "C" void kernel_launch(void* const* d_in, const int* in_sizes, int n_in,
                              void* d_out, int out_size, void* d_ws, size_t ws_size,
                              hipStream_t stream) {
    const float* qd  = (const float*)d_in[0];
    const float* kvd = (const float*)d_in[1];
    const float* bias = (const float*)d_in[2];
    const float* nbb = (const float*)d_in[3];
    const float* Wq = (const float*)d_in[4];
    const float* Wk = (const float*)d_in[5];
    const float* Wv = (const float*)d_in[6];
    const float* Wg = (const float*)d_in[7];
    const float* bg = (const float*)d_in[8];
    const float* Wo = (const float*)d_in[9];
    const float* bo = (const float*)d_in[10];
    float* out = (float*)d_out;

    __bf16* ws = (__bf16*)d_ws;
    __bf16* wsq  = ws;
    __bf16* wsk  = wsq + NTOK;
    __bf16* wsvT = wsk + NTOK;
    __bf16* wsgT = wsvT + NTOK;
    __bf16* wBF  = wsgT + NTOK;            // 5 * 65536 bf16 weights
    __bf16* qbf  = wBF + 5 * 65536;        // activations bf16 (dead after k_proj)
    __bf16* kvbf = qbf + NTOK;
    __bf16* wswa = qbf;                    // alias: written by k_attn after k_proj

    k_wcvt<<<dim3(320), 256, 0, stream>>>(Wq, Wk, Wv, Wg, Wo, wBF);
    k_acvt<<<dim3(8192), 256, 0, stream>>>(qd, kvd, qbf, kvbf);
    k_proj<<<dim3(256, 8), 256, 0, stream>>>(qbf, kvbf, wBF, bg,
                                             wsq, wsk, wsvT, wsgT);
    k_attn<<<dim3(4096), 256, 0, stream>>>(wsq, wsk, wsvT, wsgT, bias, nbb, wswa);
    k_out<<<dim3(256, 2), 256, 0, stream>>>(wswa, wBF, bo, out);
}

// Round 10
// 165.544 us; speedup vs baseline: 1.2729x; 1.1237x over previous
//
#include <hip/hip_runtime.h>
#include <hip/hip_bf16.h>

// dims
#define NB2 128
#define LQK 256
#define DIM 256
#define NH 8
#define CC 32

typedef __bf16 bf16x8 __attribute__((ext_vector_type(8)));
typedef __bf16 bf16x4 __attribute__((ext_vector_type(4)));
typedef float f32x4 __attribute__((ext_vector_type(4)));

#define MFMA16 __builtin_amdgcn_mfma_f32_16x16x32_bf16

// LDS tile row stride (bf16): 64 k + 8 pad
#define TP 72

#define NTOK ((size_t)NB2 * LQK * NH * CC)   // 8,388,608

// async global->LDS, 16B per lane; LDS dest is wave-uniform base + lane*16
static __device__ __forceinline__ void gload_lds16(const void* g, void* l) {
    __builtin_amdgcn_global_load_lds(
        (const __attribute__((address_space(1))) unsigned int*)g,
        (__attribute__((address_space(3))) unsigned int*)l,
        16, 0, 0);
}

// ---------------- Kernel 0a: weights fp32 -> bf16 -------------------------
__global__ __launch_bounds__(256) void k_wcvt(
    const float* __restrict__ Wq, const float* __restrict__ Wk,
    const float* __restrict__ Wv, const float* __restrict__ Wg,
    const float* __restrict__ Wo, __bf16* __restrict__ dst)
{
    int i = (blockIdx.x * 256 + threadIdx.x) * 4;
    int mat = i >> 16;
    int off = i & 65535;
    const float* src = (mat == 0) ? Wq : (mat == 1) ? Wk : (mat == 2) ? Wv
                      : (mat == 3) ? Wg : Wo;
    f32x4 v = *(const f32x4*)(src + off);
    __bf16* d = dst + ((size_t)mat << 16) + off;
    d[0] = (__bf16)v[0]; d[1] = (__bf16)v[1]; d[2] = (__bf16)v[2]; d[3] = (__bf16)v[3];
}

// ---------------- Kernel 0b: activations fp32 -> bf16 ---------------------
__global__ __launch_bounds__(256) void k_acvt(
    const float* __restrict__ qd, const float* __restrict__ kvd,
    __bf16* __restrict__ qbf, __bf16* __restrict__ kvbf)
{
    size_t i = ((size_t)blockIdx.x * 256 + threadIdx.x) * 8;
    const float* src;
    __bf16* dst;
    if (i < NTOK) { src = qd + i; dst = qbf + i; }
    else          { src = kvd + (i - NTOK); dst = kvbf + (i - NTOK); }
    f32x4 a = *(const f32x4*)src;
    f32x4 b = *(const f32x4*)(src + 4);
    bf16x8 r;
    r[0] = (__bf16)a[0]; r[1] = (__bf16)a[1]; r[2] = (__bf16)a[2]; r[3] = (__bf16)a[3];
    r[4] = (__bf16)b[0]; r[5] = (__bf16)b[1]; r[6] = (__bf16)b[2]; r[7] = (__bf16)b[3];
    *(bf16x8*)dst = r;
}

// ---------------- Kernel 1: QKVG projection (tiled GEMM, bf16 A) ----------
__global__ __launch_bounds__(256, 2) void k_proj(
    const __bf16* __restrict__ qbf, const __bf16* __restrict__ kvbf,
    const __bf16* __restrict__ wBF, const float* __restrict__ bg,
    __bf16* __restrict__ wsq, __bf16* __restrict__ wsk,
    __bf16* __restrict__ wsvT, __bf16* __restrict__ wsgT)
{
    __shared__ __bf16 At[2][128][TP];
    __shared__ __bf16 Bt[2][128][TP];

    const int mb = blockIdx.x, nb = blockIdx.y;
    const int t = nb >> 1;                       // 0=q 1=k 2=v 3=g
    const __bf16* X = (t == 0 || t == 3) ? qbf : kvbf;
    const __bf16* W = wBF + ((size_t)t << 16) + (size_t)((nb & 1) * 128) * 256;

    const int tid = threadIdx.x;
    const int lane = tid & 63, w = tid >> 6;
    const int g = lane >> 4, kg = g * 8, c0 = lane & 15;
    const int mq = (w >> 1) * 64, nq = (w & 1) * 64;
    const int m0 = mb * 128;
    const int srow = tid >> 1, shalf = (tid & 1) * 32;

    f32x4 acc[4][4] = {};
    bf16x8 av[4], bv[4];
    auto load_stage = [&](int kit) {
        const __bf16* ap = X + (size_t)(m0 + srow) * DIM + kit * 64 + shalf;
        const __bf16* bp = W + (size_t)srow * 256 + kit * 64 + shalf;
#pragma unroll
        for (int j = 0; j < 4; j++) {
            av[j] = *(const bf16x8*)(ap + j * 8);
            bv[j] = *(const bf16x8*)(bp + j * 8);
        }
    };
    auto write_stage = [&](int buf) {
#pragma unroll
        for (int j = 0; j < 4; j++) {
            *(bf16x8*)(&At[buf][srow][shalf + j * 8]) = av[j];
            *(bf16x8*)(&Bt[buf][srow][shalf + j * 8]) = bv[j];
        }
    };

    load_stage(0);
    write_stage(0);
    __syncthreads();

#pragma unroll
    for (int kit = 0; kit < 4; kit++) {
        if (kit < 3) load_stage(kit + 1);
        const int cur = kit & 1;
#pragma unroll
        for (int ks = 0; ks < 2; ks++) {
            bf16x8 af[4], bf_[4];
#pragma unroll
            for (int mi = 0; mi < 4; mi++)
                af[mi] = *(const bf16x8*)(&At[cur][mq + mi * 16 + c0][ks * 32 + kg]);
#pragma unroll
            for (int ni = 0; ni < 4; ni++)
                bf_[ni] = *(const bf16x8*)(&Bt[cur][nq + ni * 16 + c0][ks * 32 + kg]);
#pragma unroll
            for (int mi = 0; mi < 4; mi++)
#pragma unroll
                for (int ni = 0; ni < 4; ni++)
                    acc[mi][ni] = MFMA16(af[mi], bf_[ni], acc[mi][ni], 0, 0, 0);
        }
        if (kit < 3) write_stage(cur ^ 1);
        __syncthreads();
    }

    // ---- epilogue ----
#pragma unroll
    for (int ni = 0; ni < 4; ni++) {
        const int nloc = (nb & 1) * 128 + nq + ni * 16 + c0;
        const int h = nloc >> 5, c = nloc & 31;
        const float bg_ = (t == 3) ? bg[nloc] : 0.0f;
#pragma unroll
        for (int mi = 0; mi < 4; mi++) {
            const int mbase = m0 + mq + mi * 16 + g * 4;
            const int b2 = mbase >> 8;
            if (t == 2) {
                bf16x4 pk;
#pragma unroll
                for (int reg = 0; reg < 4; reg++) pk[reg] = (__bf16)acc[mi][ni][reg];
                *(bf16x4*)(&wsvT[((size_t)(b2 * NH + h) * CC + c) * LQK + (mbase & 255)]) = pk;
            } else if (t == 3) {
                bf16x4 pk;
#pragma unroll
                for (int reg = 0; reg < 4; reg++)
                    pk[reg] = (__bf16)(1.0f / (1.0f + __expf(-(acc[mi][ni][reg] + bg_))));
                *(bf16x4*)(&wsgT[((size_t)(b2 * NH + h) * CC + c) * LQK + (mbase & 255)]) = pk;
            } else {
#pragma unroll
                for (int reg = 0; reg < 4; reg++) {
                    const int l = (mbase + reg) & 255;
                    float v = acc[mi][ni][reg];
                    size_t idx = ((size_t)(b2 * NH + h) * LQK + l) * CC + c;
                    if (t == 0) wsq[idx] = (__bf16)(v * 0.17677669529663689f);
                    else        wsk[idx] = (__bf16)v;
                }
            }
        }
    }
}

// ---------------- Kernel 2: attention (bias+K+V via global_load_lds) ------
// grid 4096; XCD swizzle: 4 q-tiles of a head share bid%8 -> same XCD L2.
// 4 chunks of 64 k; per chunk stage bias 16KB + K 4KB + V 4KB, dbuf.
// Compute phase VMEM = 4 nbb loads only (L2-resident).
__global__ __launch_bounds__(256, 2) void k_attn(
    const __bf16* __restrict__ wsq, const __bf16* __restrict__ wsk,
    const __bf16* __restrict__ wsvT, const __bf16* __restrict__ wsgT,
    const float* __restrict__ bias, const float* __restrict__ nbb,
    __bf16* __restrict__ wswa)
{
    __shared__ float  Bl[2][64][64];    // 32 KB bias
    __shared__ __bf16 Kl[2][2048];      // 8 KB  K chunk (swizzled units)
    __shared__ __bf16 Vl[2][2048];      // 8 KB  V chunk (swizzled units)
    __shared__ __bf16 P[4][16][TP];     // 9.2 KB wave-private P

    const int tid = threadIdx.x;
    // ---- XCD head-grouping swizzle ----
    const int u0 = blockIdx.x;
    const int xcd = u0 & 7, slot = u0 >> 3;
    const int head = xcd + 8 * (slot >> 2);   // 0..1023
    const int qt = slot & 3;
    const int b2 = head >> 3, h = head & 7;

    const int lane = tid & 63, w = tid >> 6;
    const int g = lane >> 4, kg = g * 8, c0 = lane & 15;
    const int qbase = qt * 64 + w * 16;
    const int q = qbase + c0;                 // this lane's q-row
    const int rw = w * 16 + c0;               // q-row within block (0..63)

    const __bf16* qp = wsq + (size_t)(b2 * NH + h) * LQK * CC;
    const __bf16* kp = wsk + (size_t)(b2 * NH + h) * LQK * CC;
    const __bf16* vT = wsvT + (size_t)(b2 * NH + h) * CC * LQK;
    const __bf16* gT = wsgT + (size_t)(b2 * NH + h) * CC * LQK;
    const float* np = nbb + ((size_t)h * LQK + q) * LQK;
    const float* bblk = bias + ((size_t)(b2 * NH + h) * LQK + qt * 64) * LQK;

    // stage chunk c into buf: bias 16KB (4 issues/wave) + K 4KB + V 4KB (1 each)
    auto stage = [&](int buf, int c) {
        const int rbase = tid >> 4, jj = tid & 15;
#pragma unroll
        for (int i = 0; i < 4; i++) {
            const int row = i * 16 + rbase;                 // 0..63
            const int uu = jj ^ (row & 7);                  // src-unit swizzle
            gload_lds16(bblk + (size_t)row * LQK + c * 64 + uu * 4,
                        &Bl[buf][i * 16 + w * 4][0]);
        }
        {   // K: wave w covers rows w*16+(lane>>2); unit swz (L&3)^((L>>3)&3)
            const int su = (lane & 3) ^ ((lane >> 3) & 3);
            gload_lds16(kp + (size_t)(c * 64 + w * 16 + (lane >> 2)) * CC + su * 8,
                        &Kl[buf][w * 512]);
        }
        {   // V: wave w covers vT rows w*8+(lane>>3); unit swz (L&7)^(L>>3)
            const int su = (lane & 7) ^ (lane >> 3);
            gload_lds16(vT + (size_t)(w * 8 + (lane >> 3)) * LQK + c * 64 + su * 8,
                        &Vl[buf][w * 512]);
        }
    };

    bf16x8 qf = *(const bf16x8*)(qp + (size_t)q * CC + kg);

    stage(0, 0);
    __syncthreads();

    float l = 0.0f;
    f32x4 o[2] = {};

#pragma unroll
    for (int c = 0; c < 4; c++) {
        const int cur = c & 1;
        if (c < 3) stage(cur ^ 1, c + 1);     // async; drains at the barrier

        float csum = 0.0f;
#pragma unroll
        for (int j = 0; j < 4; j++) {
            // bias from LDS (swizzled), nbb direct (L2), K from LDS (swizzled)
            const int su = ((j * 4 + g) ^ (rw & 7)) * 4;
            f32x4 b4 = *(const f32x4*)(&Bl[cur][rw][su]);
            f32x4 n4 = *(const f32x4*)(np + c * 64 + j * 16 + g * 4);
            bf16x8 kf = *(const bf16x8*)(
                &Kl[cur][((j * 16 + c0) * 4 + (g ^ ((c0 >> 1) & 3))) * 8]);
            f32x4 cc;
#pragma unroll
            for (int r2 = 0; r2 < 4; r2++) cc[r2] = b4[r2] + n4[r2];
            f32x4 s = MFMA16(kf, qf, cc, 0, 0, 0);
            bf16x4 pk;
#pragma unroll
            for (int r2 = 0; r2 < 4; r2++) {
                float e = __expf(s[r2]);      // no max-sub: |s| bounded ~20
                csum += e;
                pk[r2] = (__bf16)e;
            }
            *(bf16x4*)(&P[w][c0][j * 16 + g * 4]) = pk;
        }
        l += csum;
#pragma unroll
        for (int kt2 = 0; kt2 < 2; kt2++) {
            bf16x8 pa = *(const bf16x8*)(&P[w][c0][kt2 * 32 + kg]);
#pragma unroll
            for (int vn = 0; vn < 2; vn++) {
                bf16x8 vb = *(const bf16x8*)(
                    &Vl[cur][((vn * 16 + c0) * 8 + ((kt2 * 4 + g) ^ (c0 & 7))) * 8]);
                o[vn] = MFMA16(pa, vb, o[vn], 0, 0, 0);
            }
        }
        if (c < 3) __syncthreads();           // drains stage(c+1); dbuf safety
    }

    l += __shfl_xor(l, 16);
    l += __shfl_xor(l, 32);
    const float inv = 1.0f / l;

    // ---- 1/sum, gate (transposed, bf16x4), store ----
#pragma unroll
    for (int vn = 0; vn < 2; vn++) {
        const int c = vn * 16 + c0;
        bf16x4 g4 = *(const bf16x4*)(gT + (size_t)c * LQK + qbase + g * 4);
#pragma unroll
        for (int reg = 0; reg < 4; reg++) {
            const int row = qbase + g * 4 + reg;
            const float invr = __shfl(inv, g * 4 + reg, 64);
            const float val = o[vn][reg] * invr * (float)g4[reg];
            wswa[((size_t)(b2 * LQK + row)) * (NH * CC) + h * CC + c] = (__bf16)val;
        }
    }
}

// ---------------- Kernel 3: output projection (tiled GEMM) ----------------
__global__ __launch_bounds__(256, 2) void k_out(
    const __bf16* __restrict__ wa, const __bf16* __restrict__ wBF,
    const float* __restrict__ bo, float* __restrict__ out)
{
    __shared__ __bf16 At[2][128][TP];
    __shared__ __bf16 Bt[2][128][TP];

    const int mb = blockIdx.x, nb = blockIdx.y;
    const __bf16* W = wBF + ((size_t)4 << 16) + (size_t)(nb * 128) * 256;

    const int tid = threadIdx.x;
    const int lane = tid & 63, w = tid >> 6;
    const int g = lane >> 4, kg = g * 8, c0 = lane & 15;
    const int mq = (w >> 1) * 64, nq = (w & 1) * 64;
    const int m0 = mb * 128;
    const int srow = tid >> 1, shalf = (tid & 1) * 32;

    f32x4 acc[4][4] = {};
    bf16x8 av[4], bv[4];
    auto load_stage = [&](int kit) {
        const __bf16* ap = wa + (size_t)(m0 + srow) * 256 + kit * 64 + shalf;
        const __bf16* bp = W + (size_t)srow * 256 + kit * 64 + shalf;
#pragma unroll
        for (int j = 0; j < 4; j++) {
            av[j] = *(const bf16x8*)(ap + j * 8);
            bv[j] = *(const bf16x8*)(bp + j * 8);
        }
    };
    auto write_stage = [&](int buf) {
#pragma unroll
        for (int j = 0; j < 4; j++) {
            *(bf16x8*)(&At[buf][srow][shalf + j * 8]) = av[j];
            *(bf16x8*)(&Bt[buf][srow][shalf + j * 8]) = bv[j];
        }
    };

    load_stage(0);
    write_stage(0);
    __syncthreads();

#pragma unroll
    for (int kit = 0; kit < 4; kit++) {
        if (kit < 3) load_stage(kit + 1);
        const int cur = kit & 1;
#pragma unroll
        for (int ks = 0; ks < 2; ks++) {
            bf16x8 af[4], bf_[4];
#pragma unroll
            for (int mi = 0; mi < 4; mi++)
                af[mi] = *(const bf16x8*)(&At[cur][mq + mi * 16 + c0][ks * 32 + kg]);
#pragma unroll
            for (int ni = 0; ni < 4; ni++)
                bf_[ni] = *(const bf16x8*)(&Bt[cur][nq + ni * 16 + c0][ks * 32 + kg]);
#pragma unroll
            for (int mi = 0; mi < 4; mi++)
#pragma unroll
                for (int ni = 0; ni < 4; ni++)
                    acc[mi][ni] = MFMA16(af[mi], bf_[ni], acc[mi][ni], 0, 0, 0);
        }
        if (kit < 3) write_stage(cur ^ 1);
        __syncthreads();
    }

#pragma unroll
    for (int ni = 0; ni < 4; ni++) {
        const int n = nb * 128 + nq + ni * 16 + c0;
        const float bo_ = bo[n];
#pragma unroll
        for (int mi = 0; mi < 4; mi++) {
            const int mbase = m0 + mq + mi * 16 + g * 4;
#pragma unroll
            for (int reg = 0; reg < 4; reg++)
                out[(size_t)(mbase + reg) * 256 + n] = acc[mi][ni][reg] + bo_;
        }
    }
}

// ---------------- launcher ------------------------------------------------
extern "C" void kernel_launch(void* const* d_in, const int* in_sizes, int n_in,
                              void* d_out, int out_size, void* d_ws, size_t ws_size,
                              hipStream_t stream) {
    const float* qd  = (const float*)d_in[0];
    const float* kvd = (const float*)d_in[1];
    const float* bias = (const float*)d_in[2];
    const float* nbb = (const float*)d_in[3];
    const float* Wq = (const float*)d_in[4];
    const float* Wk = (const float*)d_in[5];
    const float* Wv = (const float*)d_in[6];
    const float* Wg = (const float*)d_in[7];
    const float* bg = (const float*)d_in[8];
    const float* Wo = (const float*)d_in[9];
    const float* bo = (const float*)d_in[10];
    float* out = (float*)d_out;

    __bf16* ws = (__bf16*)d_ws;
    __bf16* wsq  = ws;
    __bf16* wsk  = wsq + NTOK;
    __bf16* wsvT = wsk + NTOK;
    __bf16* wsgT = wsvT + NTOK;
    __bf16* wBF  = wsgT + NTOK;            // 5 * 65536 bf16 weights
    __bf16* qbf  = wBF + 5 * 65536;        // activations bf16 (dead after k_proj)
    __bf16* kvbf = qbf + NTOK;
    __bf16* wswa = qbf;                    // alias: written by k_attn after k_proj

    k_wcvt<<<dim3(320), 256, 0, stream>>>(Wq, Wk, Wv, Wg, Wo, wBF);
    k_acvt<<<dim3(8192), 256, 0, stream>>>(qd, kvd, qbf, kvbf);
    k_proj<<<dim3(256, 8), 256, 0, stream>>>(qbf, kvbf, wBF, bg,
                                             wsq, wsk, wsvT, wsgT);
    k_attn<<<dim3(4096), 256, 0, stream>>>(wsq, wsk, wsvT, wsgT, bias, nbb, wswa);
    k_out<<<dim3(256, 2), 256, 0, stream>>>(wswa, wBF, bo, out);
}